// Round 1
// baseline (1732.758 us; speedup 1.0000x reference)
//
#include <hip/hip_runtime.h>
#include <stdint.h>

#define BB 4
#define LL 2048
#define DD 2048
#define NS 64
#define RR 128
#define PP 256
#define MM (BB*LL)

typedef __bf16 bf16x8 __attribute__((ext_vector_type(8)));
typedef float f32x4 __attribute__((ext_vector_type(4)));
typedef unsigned short ushx8 __attribute__((ext_vector_type(8)));
typedef unsigned short ushx4 __attribute__((ext_vector_type(4)));

__device__ __forceinline__ unsigned short f2bf(float f) {
  unsigned int u = __builtin_bit_cast(unsigned int, f);
  u = (u + 0x7FFFu + ((u >> 16) & 1u)) >> 16;
  return (unsigned short)u;
}
__device__ __forceinline__ float bf2f(unsigned short s) {
  return __builtin_bit_cast(float, ((unsigned int)s) << 16);
}
__device__ __forceinline__ void gll16(const void* g, void* l) {
  __builtin_amdgcn_global_load_lds(
      (const __attribute__((address_space(1))) unsigned int*)g,
      (__attribute__((address_space(3))) unsigned int*)l, 16, 0, 0);
}
__device__ __forceinline__ float softplus_f(float z) {
  return (z > 20.f) ? z : log1pf(__expf(z));
}

// ---------------- LayerNorm: (B*L, D) f32 -> bf16 ----------------
__global__ __launch_bounds__(256) void ln_kernel(
    const float* __restrict__ x, const float* __restrict__ w,
    const float* __restrict__ bp, unsigned short* __restrict__ xn16) {
  const int row = blockIdx.x, t = threadIdx.x;
  const float* xr = x + (size_t)row * DD;
  const float4 a = *(const float4*)(xr + t*8);
  const float4 b = *(const float4*)(xr + t*8 + 4);
  float s = (a.x+a.y)+(a.z+a.w)+(b.x+b.y)+(b.z+b.w);
  float q = (a.x*a.x+a.y*a.y)+(a.z*a.z+a.w*a.w)+(b.x*b.x+b.y*b.y)+(b.z*b.z+b.w*b.w);
  #pragma unroll
  for (int off = 32; off; off >>= 1) { s += __shfl_xor(s, off); q += __shfl_xor(q, off); }
  __shared__ float ss[4], sq[4];
  if ((t & 63) == 0) { ss[t>>6] = s; sq[t>>6] = q; }
  __syncthreads();
  s = (ss[0]+ss[1])+(ss[2]+ss[3]);
  q = (sq[0]+sq[1])+(sq[2]+sq[3]);
  const float mu = s * (1.0f/DD);
  const float rstd = rsqrtf(q*(1.0f/DD) - mu*mu + 1e-5f);
  const float4 w0 = *(const float4*)(w + t*8), w1 = *(const float4*)(w + t*8+4);
  const float4 b0 = *(const float4*)(bp + t*8), b1 = *(const float4*)(bp + t*8+4);
  ushx8 o;
  o[0]=f2bf((a.x-mu)*rstd*w0.x+b0.x);
  o[1]=f2bf((a.y-mu)*rstd*w0.y+b0.y);
  o[2]=f2bf((a.z-mu)*rstd*w0.z+b0.z);
  o[3]=f2bf((a.w-mu)*rstd*w0.w+b0.w);
  o[4]=f2bf((b.x-mu)*rstd*w1.x+b1.x);
  o[5]=f2bf((b.y-mu)*rstd*w1.y+b1.y);
  o[6]=f2bf((b.z-mu)*rstd*w1.z+b1.z);
  o[7]=f2bf((b.w-mu)*rstd*w1.w+b1.w);
  *(ushx8*)(xn16 + (size_t)row*DD + t*8) = o;
}

// ---------------- f32 -> bf16 converters ----------------
__global__ __launch_bounds__(256) void f2bf_kernel(const float* __restrict__ in,
    unsigned short* __restrict__ out, int n4) {
  const int i = blockIdx.x*256 + threadIdx.x;
  if (i < n4) {
    const float4 v = *(const float4*)(in + (size_t)i*4);
    ushx4 o; o[0]=f2bf(v.x); o[1]=f2bf(v.y); o[2]=f2bf(v.z); o[3]=f2bf(v.w);
    *(ushx4*)(out + (size_t)i*4) = o;
  }
}

// delta cols (first 128 of proj's 256) -> bf16 (MM x RR)
__global__ __launch_bounds__(256) void cvt_delta_kernel(const float* __restrict__ proj,
    unsigned short* __restrict__ out) {
  const int i = blockIdx.x*256 + threadIdx.x;    // MM*RR/4 total
  const int m = i >> 5, r4 = (i & 31) << 2;
  const float4 v = *(const float4*)(proj + (size_t)m*PP + r4);
  ushx4 o; o[0]=f2bf(v.x); o[1]=f2bf(v.y); o[2]=f2bf(v.z); o[3]=f2bf(v.w);
  *(ushx4*)(out + (size_t)m*RR + r4) = o;
}

// ---------------- bf16 NT GEMM: C(M,N) = A(M,K) @ W(N,K)^T ----------------
// 128x128 tile, BK=32, 4 waves (2x2), 4x4 16x16x32 MFMA frags per wave.
template<int EPI>
__global__ __launch_bounds__(256) void gemm_bt(
    const unsigned short* __restrict__ A, const unsigned short* __restrict__ W,
    float* __restrict__ C, const float* __restrict__ bias,
    int M, int N, int K) {
  __shared__ unsigned short As[128*32];
  __shared__ unsigned short Bs[128*32];
  const int tid = threadIdx.x;
  const int lane = tid & 63;
  const int wv = tid >> 6;
  const int nb = N >> 7;
  const int m0 = (blockIdx.x / nb) << 7;
  const int n0 = (blockIdx.x % nb) << 7;
  const int wr = wv >> 1, wc = wv & 1;
  f32x4 acc[4][4] = {};
  const int c0 = tid, c1 = tid + 256;
  const unsigned short* Ag0 = A + (size_t)(m0 + (c0>>2))*K + (c0&3)*8;
  const unsigned short* Ag1 = A + (size_t)(m0 + (c1>>2))*K + (c1&3)*8;
  const unsigned short* Wg0 = W + (size_t)(n0 + (c0>>2))*K + (c0&3)*8;
  const unsigned short* Wg1 = W + (size_t)(n0 + (c1>>2))*K + (c1&3)*8;
  const int ar = (wr<<6) + (lane & 15);
  const int br = (wc<<6) + (lane & 15);
  const int kk = (lane >> 4) << 3;
  for (int k0 = 0; k0 < K; k0 += 32) {
    __syncthreads();
    gll16(Ag0 + k0, &As[c0*8]);
    gll16(Ag1 + k0, &As[c1*8]);
    gll16(Wg0 + k0, &Bs[c0*8]);
    gll16(Wg1 + k0, &Bs[c1*8]);
    __syncthreads();
    bf16x8 af[4], bw[4];
    #pragma unroll
    for (int i = 0; i < 4; ++i) af[i] = *(const bf16x8*)&As[(ar + i*16)*32 + kk];
    #pragma unroll
    for (int j = 0; j < 4; ++j) bw[j] = *(const bf16x8*)&Bs[(br + j*16)*32 + kk];
    #pragma unroll
    for (int i = 0; i < 4; ++i)
      #pragma unroll
      for (int j = 0; j < 4; ++j)
        acc[i][j] = __builtin_amdgcn_mfma_f32_16x16x32_bf16(af[i], bw[j], acc[i][j], 0, 0, 0);
  }
  const int orow = m0 + (wr<<6) + ((lane>>4)<<2);
  const int ocol = n0 + (wc<<6) + (lane & 15);
  #pragma unroll
  for (int i = 0; i < 4; ++i) {
    #pragma unroll
    for (int j = 0; j < 4; ++j) {
      const int col = ocol + j*16;
      const float bi = (EPI==1) ? bias[col] : 0.f;
      #pragma unroll
      for (int r = 0; r < 4; ++r) {
        float v = acc[i][j][r];
        if (EPI==1) v = softplus_f(v + bi);
        C[(size_t)(orow + i*16 + r)*N + col] = v;
      }
    }
  }
}

// ---------------- selective scan ----------------
// Block: 512 threads = 8 waves = 8 consecutive d-channels of one batch.
// Lane = state n (N=64). B/C tiles staged in LDS (shared across the 8 channels).
__global__ __launch_bounds__(512) void scan_kernel(
    const float* __restrict__ dt, const unsigned short* __restrict__ xn,
    const float* __restrict__ proj, const float* __restrict__ A_log,
    float* __restrict__ y) {
  __shared__ float Bl[64*64];
  __shared__ float Cl[64*64];
  __shared__ float dtl[64*8];
  __shared__ float dtxl[64*8];
  __shared__ float yl[64*8];
  const int tid = threadIdx.x;
  const int lane = tid & 63, wv = tid >> 6;
  const int chb = blockIdx.x * 8;
  const int b = chb >> 11;
  const int d0 = chb & (DD-1);
  const float Al2 = -__expf(A_log[(size_t)(d0 + wv)*NS + lane]) * 1.44269504088896340736f;
  const float* projB = proj + (size_t)b*LL*PP;
  const int sj = tid >> 3, sc = tid & 7;
  float h = 0.f;
  for (int o = 0; o < 32; ++o) {
    const int l0 = o << 6;
    const int l0c = (o & 7) << 6;
    __syncthreads();
    {
      const int c0 = tid, c1 = tid + 512;
      gll16(projB + (size_t)(l0 + (c0>>4))*PP + 128 + ((c0&15)<<2), &Bl[c0<<2]);
      gll16(projB + (size_t)(l0 + (c1>>4))*PP + 128 + ((c1&15)<<2), &Bl[c1<<2]);
      gll16(projB + (size_t)(l0c + (c0>>4))*PP + 192 + ((c0&15)<<2), &Cl[c0<<2]);
      gll16(projB + (size_t)(l0c + (c1>>4))*PP + 192 + ((c1&15)<<2), &Cl[c1<<2]);
      const size_t g = (size_t)(b*LL + l0 + sj)*DD + d0 + sc;
      const float dv = dt[g];
      const float xv = bf2f(xn[g]);
      dtl[sj*8+sc] = dv;
      dtxl[sj*8+sc] = dv * xv;
    }
    __syncthreads();
    #pragma unroll
    for (int j = 0; j < 64; ++j) {
      const float sdt  = dtl[j*8 + wv];
      const float sdtx = dtxl[j*8 + wv];
      const float Bn = Bl[(j<<6) + lane];
      const float Cn = Cl[(j<<6) + lane];
      const float dA = exp2f(sdt * Al2);
      h = fmaf(dA, h, sdtx * Bn);
      float p = h * Cn;
      #pragma unroll
      for (int off = 32; off; off >>= 1) p += __shfl_xor(p, off);
      if (lane == j) yl[(j<<3) + wv] = p;
    }
    __syncthreads();
    y[(size_t)(b*LL + l0 + sj)*DD + d0 + sc] = yl[sj*8 + sc];
  }
}

// ---------------- fuse: G = bf16(y + x*Dp) elementwise ----------------
__global__ __launch_bounds__(256) void fuse_g_kernel(
    const float* __restrict__ y, const float* __restrict__ x,
    const float* __restrict__ Dp, unsigned short* __restrict__ G) {
  const size_t i4 = ((size_t)blockIdx.x*256 + threadIdx.x) * 4;
  const float4 yv = *(const float4*)(y + i4);
  const float4 xv = *(const float4*)(x + i4);
  const float4 dp = *(const float4*)(Dp + (i4 & (DD-1)));
  ushx4 o;
  o[0] = f2bf(fmaf(xv.x, dp.x, yv.x));
  o[1] = f2bf(fmaf(xv.y, dp.y, yv.y));
  o[2] = f2bf(fmaf(xv.z, dp.z, yv.z));
  o[3] = f2bf(fmaf(xv.w, dp.w, yv.w));
  *(ushx4*)(G + i4) = o;
}

extern "C" void kernel_launch(void* const* d_in, const int* in_sizes, int n_in,
                              void* d_out, int out_size, void* d_ws, size_t ws_size,
                              hipStream_t stream) {
  const float* x    = (const float*)d_in[0];
  const float* nw   = (const float*)d_in[1];
  const float* nb_  = (const float*)d_in[2];
  const float* xpw  = (const float*)d_in[3];
  const float* dtw  = (const float*)d_in[4];
  const float* dtb  = (const float*)d_in[5];
  const float* alog = (const float*)d_in[6];
  const float* dpar = (const float*)d_in[7];
  const float* opw  = (const float*)d_in[8];
  float* out = (float*)d_out;
  char* ws = (char*)d_ws;

  unsigned short* xn16    = (unsigned short*)(ws + 0);          // 33,554,432
  float*          proj    = (float*)(ws + 33554432);            //  8,388,608
  unsigned short* delta16 = (unsigned short*)(ws + 41943040);   //  2,097,152
  float*          dt32    = (float*)(ws + 44040192);            // 67,108,864
  unsigned short* xpw16   = (unsigned short*)(ws + 111149056);  //  1,048,576
  unsigned short* dtw16   = (unsigned short*)(ws + 112197632);  //    524,288
  unsigned short* opw16   = (unsigned short*)(ws + 112721920);  //  8,388,608
  unsigned short* g16     = (unsigned short*)(ws + 121110528);  // 33,554,432

  ln_kernel<<<dim3(MM), dim3(256), 0, stream>>>(x, nw, nb_, xn16);
  f2bf_kernel<<<dim3(512), dim3(256), 0, stream>>>(xpw, xpw16, 131072);
  f2bf_kernel<<<dim3(256), dim3(256), 0, stream>>>(dtw, dtw16, 65536);
  f2bf_kernel<<<dim3(4096), dim3(256), 0, stream>>>(opw, opw16, 1048576);
  // proj = xn @ x_proj_w^T : (8192,256,K=2048)
  gemm_bt<0><<<dim3(128), dim3(256), 0, stream>>>(xn16, xpw16, proj, (const float*)nullptr, MM, PP, DD);
  cvt_delta_kernel<<<dim3(1024), dim3(256), 0, stream>>>(proj, delta16);
  // dt = softplus(delta_r @ dt_proj_w^T + b) : (8192,2048,K=128)
  gemm_bt<1><<<dim3(1024), dim3(256), 0, stream>>>(delta16, dtw16, dt32, dtb, MM, DD, RR);
  // selective scan -> y (stored in d_out as scratch, row-major (B*L, D))
  scan_kernel<<<dim3(1024), dim3(512), 0, stream>>>(dt32, xn16, proj, alog, out);
  // G = bf16(y + x*D)
  fuse_g_kernel<<<dim3(16384), dim3(256), 0, stream>>>(out, x, dpar, g16);
  // out = G @ out_proj_w^T : (8192,2048,K=2048)
  gemm_bt<0><<<dim3(1024), dim3(256), 0, stream>>>(g16, opw16, out, (const float*)nullptr, MM, DD, DD);
}

// Round 2
// 648.827 us; speedup vs baseline: 2.6706x; 2.6706x over previous
//
#include <hip/hip_runtime.h>
#include <stdint.h>

#define BB 4
#define LL 2048
#define DD 2048
#define NS 64
#define RR 128
#define PP 256
#define MM (BB*LL)
#define LOG2E 1.44269504088896340736f

typedef __bf16 bf16x8 __attribute__((ext_vector_type(8)));
typedef float f32x4 __attribute__((ext_vector_type(4)));
typedef unsigned short ushx8 __attribute__((ext_vector_type(8)));
typedef unsigned short ushx4 __attribute__((ext_vector_type(4)));
typedef unsigned int u32;

__device__ __forceinline__ unsigned short f2bf(float f) {
  unsigned int u = __builtin_bit_cast(unsigned int, f);
  u = (u + 0x7FFFu + ((u >> 16) & 1u)) >> 16;
  return (unsigned short)u;
}
__device__ __forceinline__ float bf2f(unsigned short s) {
  return __builtin_bit_cast(float, ((unsigned int)s) << 16);
}
__device__ __forceinline__ void gll16(const void* g, void* l) {
  __builtin_amdgcn_global_load_lds(
      (const __attribute__((address_space(1))) unsigned int*)g,
      (__attribute__((address_space(3))) unsigned int*)l, 16, 0, 0);
}
__device__ __forceinline__ float softplus_f(float z) {
  return (z > 20.f) ? z : log1pf(__expf(z));
}
template<int N>
__device__ __forceinline__ float dpp_shr(float v) {
  // row_shr:N, bound_ctrl=true -> shifted-in lanes read 0 (sum-safe)
  int t = __builtin_amdgcn_update_dpp(0, __builtin_bit_cast(int, v),
                                      0x110 | N, 0xf, 0xf, true);
  return __builtin_bit_cast(float, t);
}
__device__ __forceinline__ float readlane_f(float v, int l) {
  return __builtin_bit_cast(float, __builtin_amdgcn_readlane(__builtin_bit_cast(int, v), l));
}
__device__ __forceinline__ void unpk(u32 u, float& lo, float& hi) {
  lo = __builtin_bit_cast(float, u << 16);
  hi = __builtin_bit_cast(float, u & 0xFFFF0000u);
}

// ---------------- LayerNorm: (B*L, D) f32 -> bf16 ----------------
__global__ __launch_bounds__(256) void ln_kernel(
    const float* __restrict__ x, const float* __restrict__ w,
    const float* __restrict__ bp, unsigned short* __restrict__ xn16) {
  const int row = blockIdx.x, t = threadIdx.x;
  const float* xr = x + (size_t)row * DD;
  const float4 a = *(const float4*)(xr + t*8);
  const float4 b = *(const float4*)(xr + t*8 + 4);
  float s = (a.x+a.y)+(a.z+a.w)+(b.x+b.y)+(b.z+b.w);
  float q = (a.x*a.x+a.y*a.y)+(a.z*a.z+a.w*a.w)+(b.x*b.x+b.y*b.y)+(b.z*b.z+b.w*b.w);
  #pragma unroll
  for (int off = 32; off; off >>= 1) { s += __shfl_xor(s, off); q += __shfl_xor(q, off); }
  __shared__ float ss[4], sq[4];
  if ((t & 63) == 0) { ss[t>>6] = s; sq[t>>6] = q; }
  __syncthreads();
  s = (ss[0]+ss[1])+(ss[2]+ss[3]);
  q = (sq[0]+sq[1])+(sq[2]+sq[3]);
  const float mu = s * (1.0f/DD);
  const float rstd = rsqrtf(q*(1.0f/DD) - mu*mu + 1e-5f);
  const float4 w0 = *(const float4*)(w + t*8), w1 = *(const float4*)(w + t*8+4);
  const float4 b0 = *(const float4*)(bp + t*8), b1 = *(const float4*)(bp + t*8+4);
  ushx8 o;
  o[0]=f2bf((a.x-mu)*rstd*w0.x+b0.x);
  o[1]=f2bf((a.y-mu)*rstd*w0.y+b0.y);
  o[2]=f2bf((a.z-mu)*rstd*w0.z+b0.z);
  o[3]=f2bf((a.w-mu)*rstd*w0.w+b0.w);
  o[4]=f2bf((b.x-mu)*rstd*w1.x+b1.x);
  o[5]=f2bf((b.y-mu)*rstd*w1.y+b1.y);
  o[6]=f2bf((b.z-mu)*rstd*w1.z+b1.z);
  o[7]=f2bf((b.w-mu)*rstd*w1.w+b1.w);
  *(ushx8*)(xn16 + (size_t)row*DD + t*8) = o;
}

// ---------------- f32 -> bf16 converters ----------------
__global__ __launch_bounds__(256) void f2bf_kernel(const float* __restrict__ in,
    unsigned short* __restrict__ out, int n4) {
  const int i = blockIdx.x*256 + threadIdx.x;
  if (i < n4) {
    const float4 v = *(const float4*)(in + (size_t)i*4);
    ushx4 o; o[0]=f2bf(v.x); o[1]=f2bf(v.y); o[2]=f2bf(v.z); o[3]=f2bf(v.w);
    *(ushx4*)(out + (size_t)i*4) = o;
  }
}

// delta cols (first 128 of proj's 256) -> bf16 (MM x RR)
__global__ __launch_bounds__(256) void cvt_delta_kernel(const float* __restrict__ proj,
    unsigned short* __restrict__ out) {
  const int i = blockIdx.x*256 + threadIdx.x;    // MM*RR/4 total
  const int m = i >> 5, r4 = (i & 31) << 2;
  const float4 v = *(const float4*)(proj + (size_t)m*PP + r4);
  ushx4 o; o[0]=f2bf(v.x); o[1]=f2bf(v.y); o[2]=f2bf(v.z); o[3]=f2bf(v.w);
  *(ushx4*)(out + (size_t)m*RR + r4) = o;
}

// ---------------- bf16 NT GEMM: C(M,N) = A(M,K) @ W(N,K)^T ----------------
template<int EPI>
__global__ __launch_bounds__(256) void gemm_bt(
    const unsigned short* __restrict__ A, const unsigned short* __restrict__ W,
    float* __restrict__ C, const float* __restrict__ bias,
    int M, int N, int K) {
  __shared__ unsigned short As[128*32];
  __shared__ unsigned short Bs[128*32];
  const int tid = threadIdx.x;
  const int lane = tid & 63;
  const int wv = tid >> 6;
  const int nb = N >> 7;
  const int m0 = (blockIdx.x / nb) << 7;
  const int n0 = (blockIdx.x % nb) << 7;
  const int wr = wv >> 1, wc = wv & 1;
  f32x4 acc[4][4] = {};
  const int c0 = tid, c1 = tid + 256;
  const unsigned short* Ag0 = A + (size_t)(m0 + (c0>>2))*K + (c0&3)*8;
  const unsigned short* Ag1 = A + (size_t)(m0 + (c1>>2))*K + (c1&3)*8;
  const unsigned short* Wg0 = W + (size_t)(n0 + (c0>>2))*K + (c0&3)*8;
  const unsigned short* Wg1 = W + (size_t)(n0 + (c1>>2))*K + (c1&3)*8;
  const int ar = (wr<<6) + (lane & 15);
  const int br = (wc<<6) + (lane & 15);
  const int kk = (lane >> 4) << 3;
  for (int k0 = 0; k0 < K; k0 += 32) {
    __syncthreads();
    gll16(Ag0 + k0, &As[c0*8]);
    gll16(Ag1 + k0, &As[c1*8]);
    gll16(Wg0 + k0, &Bs[c0*8]);
    gll16(Wg1 + k0, &Bs[c1*8]);
    __syncthreads();
    bf16x8 af[4], bw[4];
    #pragma unroll
    for (int i = 0; i < 4; ++i) af[i] = *(const bf16x8*)&As[(ar + i*16)*32 + kk];
    #pragma unroll
    for (int j = 0; j < 4; ++j) bw[j] = *(const bf16x8*)&Bs[(br + j*16)*32 + kk];
    #pragma unroll
    for (int i = 0; i < 4; ++i)
      #pragma unroll
      for (int j = 0; j < 4; ++j)
        acc[i][j] = __builtin_amdgcn_mfma_f32_16x16x32_bf16(af[i], bw[j], acc[i][j], 0, 0, 0);
  }
  const int orow = m0 + (wr<<6) + ((lane>>4)<<2);
  const int ocol = n0 + (wc<<6) + (lane & 15);
  #pragma unroll
  for (int i = 0; i < 4; ++i) {
    #pragma unroll
    for (int j = 0; j < 4; ++j) {
      const int col = ocol + j*16;
      const float bi = (EPI==1) ? bias[col] : 0.f;
      #pragma unroll
      for (int r = 0; r < 4; ++r) {
        float v = acc[i][j][r];
        if (EPI==1) v = softplus_f(v + bi);
        C[(size_t)(orow + i*16 + r)*N + col] = v;
      }
    }
  }
}

// ---------------- selective scan (v2) ----------------
// Block: 256 thr = 4 waves; 16 d-channels per block; 512 blocks = 4 batches x 128.
// Wave: 4 channels x 16 lanes; each lane owns 4 states (n = 4q..4q+3).
// Inner loop per step: 2x ds_read_b64 (B,C bf16) + 2x ds_read_b32 broadcast (dt,dtx);
// n-reduce = 4x DPP row_shr adds (pure VALU); y kept in regs via readlane+cndmask.
__global__ __launch_bounds__(256) void scan_kernel(
    const float* __restrict__ dt, const unsigned short* __restrict__ xn,
    const float* __restrict__ proj, const float* __restrict__ A_log,
    float* __restrict__ y) {
  __shared__ unsigned short Bl[64*68];   // [l][n] bf16, row stride 68
  __shared__ unsigned short Cl[64*68];
  __shared__ float dtl[64*17];           // [l][ch], pad 17
  __shared__ float dtxl[64*17];
  __shared__ float ylT[16*66];           // [ch][l], pad 66
  const int tid = threadIdx.x;
  const int lane = tid & 63, wv = tid >> 6;
  const int b  = blockIdx.x >> 7;
  const int d0 = (blockIdx.x & 127) << 4;
  const int q = lane & 15, r = lane >> 4;
  const int ch = (wv << 2) + r;          // 0..15 within block
  const int d  = d0 + ch;
  float a2[4];
  #pragma unroll
  for (int k = 0; k < 4; ++k)
    a2[k] = -__expf(A_log[(size_t)d*NS + (q<<2) + k]) * LOG2E;
  const float* projB = proj + (size_t)b*LL*PP;
  const size_t rowbase = (size_t)b*LL;
  float h0=0.f, h1=0.f, h2=0.f, h3=0.f;
  float yr0=0.f, yr1=0.f, yr2=0.f, yr3=0.f;
  const int sl = tid >> 2;               // staging row 0..63
  const int sn = (tid & 3) << 4;         // staging col group (B/C)
  const int sc4 = (tid & 3) << 2;        // staging col group (dt)
  for (int o = 0; o < 32; ++o) {
    const int l0 = o << 6;
    const int l0c = (o & 7) << 6;
    // ---- stage B, C (f32 -> bf16), dt, dtx ----
    {
      #pragma unroll
      for (int s = 0; s < 2; ++s) {
        const float4 v0 = *(const float4*)&projB[(size_t)(l0 + sl)*PP + 128 + sn + 8*s];
        const float4 v1 = *(const float4*)&projB[(size_t)(l0 + sl)*PP + 128 + sn + 8*s + 4];
        ushx4 w0, w1;
        w0[0]=f2bf(v0.x); w0[1]=f2bf(v0.y); w0[2]=f2bf(v0.z); w0[3]=f2bf(v0.w);
        w1[0]=f2bf(v1.x); w1[1]=f2bf(v1.y); w1[2]=f2bf(v1.z); w1[3]=f2bf(v1.w);
        *(ushx4*)&Bl[sl*68 + sn + 8*s]     = w0;
        *(ushx4*)&Bl[sl*68 + sn + 8*s + 4] = w1;
      }
      #pragma unroll
      for (int s = 0; s < 2; ++s) {
        const float4 v0 = *(const float4*)&projB[(size_t)(l0c + sl)*PP + 192 + sn + 8*s];
        const float4 v1 = *(const float4*)&projB[(size_t)(l0c + sl)*PP + 192 + sn + 8*s + 4];
        ushx4 w0, w1;
        w0[0]=f2bf(v0.x); w0[1]=f2bf(v0.y); w0[2]=f2bf(v0.z); w0[3]=f2bf(v0.w);
        w1[0]=f2bf(v1.x); w1[1]=f2bf(v1.y); w1[2]=f2bf(v1.z); w1[3]=f2bf(v1.w);
        *(ushx4*)&Cl[sl*68 + sn + 8*s]     = w0;
        *(ushx4*)&Cl[sl*68 + sn + 8*s + 4] = w1;
      }
      const size_t g = (rowbase + l0 + sl)*(size_t)DD + d0 + sc4;
      const float4 dv = *(const float4*)&dt[g];
      const ushx4 xv = *(const ushx4*)&xn[g];
      dtl [sl*17 + sc4 + 0] = dv.x;  dtxl[sl*17 + sc4 + 0] = dv.x * bf2f(xv[0]);
      dtl [sl*17 + sc4 + 1] = dv.y;  dtxl[sl*17 + sc4 + 1] = dv.y * bf2f(xv[1]);
      dtl [sl*17 + sc4 + 2] = dv.z;  dtxl[sl*17 + sc4 + 2] = dv.z * bf2f(xv[2]);
      dtl [sl*17 + sc4 + 3] = dv.w;  dtxl[sl*17 + sc4 + 3] = dv.w * bf2f(xv[3]);
    }
    __syncthreads();
    // ---- 64 scan steps ----
    #pragma unroll 8
    for (int j = 0; j < 64; ++j) {
      const float sdt  = dtl [j*17 + ch];
      const float sdtx = dtxl[j*17 + ch];
      const uint2 Bu = *(const uint2*)&Bl[j*68 + (q<<2)];
      const uint2 Cu = *(const uint2*)&Cl[j*68 + (q<<2)];
      float B0,B1,B2,B3, C0,C1,C2,C3;
      unpk(Bu.x, B0, B1); unpk(Bu.y, B2, B3);
      unpk(Cu.x, C0, C1); unpk(Cu.y, C2, C3);
      const float dA0 = __builtin_amdgcn_exp2f(sdt * a2[0]);
      const float dA1 = __builtin_amdgcn_exp2f(sdt * a2[1]);
      const float dA2 = __builtin_amdgcn_exp2f(sdt * a2[2]);
      const float dA3 = __builtin_amdgcn_exp2f(sdt * a2[3]);
      h0 = fmaf(dA0, h0, sdtx * B0);
      h1 = fmaf(dA1, h1, sdtx * B1);
      h2 = fmaf(dA2, h2, sdtx * B2);
      h3 = fmaf(dA3, h3, sdtx * B3);
      float p = fmaf(h3, C3, fmaf(h2, C2, fmaf(h1, C1, h0 * C0)));
      p += dpp_shr<1>(p);
      p += dpp_shr<2>(p);
      p += dpp_shr<4>(p);
      p += dpp_shr<8>(p);           // lane 16r+15 holds channel (4wv+r) sum
      const float s0 = readlane_f(p, 15);
      const float s1 = readlane_f(p, 31);
      const float s2 = readlane_f(p, 47);
      const float s3 = readlane_f(p, 63);
      const bool sel = (lane == j);
      yr0 = sel ? s0 : yr0;
      yr1 = sel ? s1 : yr1;
      yr2 = sel ? s2 : yr2;
      yr3 = sel ? s3 : yr3;
    }
    // ---- funnel y: regs -> ylT -> global (coalesced) ----
    ylT[((wv<<2)+0)*66 + lane] = yr0;
    ylT[((wv<<2)+1)*66 + lane] = yr1;
    ylT[((wv<<2)+2)*66 + lane] = yr2;
    ylT[((wv<<2)+3)*66 + lane] = yr3;
    __syncthreads();
    {
      const int dc = tid & 15, dl0 = tid >> 4;
      #pragma unroll
      for (int pp2 = 0; pp2 < 4; ++pp2) {
        const int l = dl0 + (pp2 << 4);
        y[(rowbase + l0 + l)*(size_t)DD + d0 + dc] = ylT[dc*66 + l];
      }
    }
  }
}

// ---------------- fuse: G = bf16(y + x*Dp) elementwise ----------------
__global__ __launch_bounds__(256) void fuse_g_kernel(
    const float* __restrict__ y, const float* __restrict__ x,
    const float* __restrict__ Dp, unsigned short* __restrict__ G) {
  const size_t i4 = ((size_t)blockIdx.x*256 + threadIdx.x) * 4;
  const float4 yv = *(const float4*)(y + i4);
  const float4 xv = *(const float4*)(x + i4);
  const float4 dp = *(const float4*)(Dp + (i4 & (DD-1)));
  ushx4 o;
  o[0] = f2bf(fmaf(xv.x, dp.x, yv.x));
  o[1] = f2bf(fmaf(xv.y, dp.y, yv.y));
  o[2] = f2bf(fmaf(xv.z, dp.z, yv.z));
  o[3] = f2bf(fmaf(xv.w, dp.w, yv.w));
  *(ushx4*)(G + i4) = o;
}

extern "C" void kernel_launch(void* const* d_in, const int* in_sizes, int n_in,
                              void* d_out, int out_size, void* d_ws, size_t ws_size,
                              hipStream_t stream) {
  const float* x    = (const float*)d_in[0];
  const float* nw   = (const float*)d_in[1];
  const float* nb_  = (const float*)d_in[2];
  const float* xpw  = (const float*)d_in[3];
  const float* dtw  = (const float*)d_in[4];
  const float* dtb  = (const float*)d_in[5];
  const float* alog = (const float*)d_in[6];
  const float* dpar = (const float*)d_in[7];
  const float* opw  = (const float*)d_in[8];
  float* out = (float*)d_out;
  char* ws = (char*)d_ws;

  unsigned short* xn16    = (unsigned short*)(ws + 0);          // 33,554,432
  float*          proj    = (float*)(ws + 33554432);            //  8,388,608
  unsigned short* delta16 = (unsigned short*)(ws + 41943040);   //  2,097,152
  float*          dt32    = (float*)(ws + 44040192);            // 67,108,864
  unsigned short* xpw16   = (unsigned short*)(ws + 111149056);  //  1,048,576
  unsigned short* dtw16   = (unsigned short*)(ws + 112197632);  //    524,288
  unsigned short* opw16   = (unsigned short*)(ws + 112721920);  //  8,388,608
  unsigned short* g16     = (unsigned short*)(ws + 121110528);  // 33,554,432

  ln_kernel<<<dim3(MM), dim3(256), 0, stream>>>(x, nw, nb_, xn16);
  f2bf_kernel<<<dim3(512), dim3(256), 0, stream>>>(xpw, xpw16, 131072);
  f2bf_kernel<<<dim3(256), dim3(256), 0, stream>>>(dtw, dtw16, 65536);
  f2bf_kernel<<<dim3(4096), dim3(256), 0, stream>>>(opw, opw16, 1048576);
  // proj = xn @ x_proj_w^T : (8192,256,K=2048)
  gemm_bt<0><<<dim3(128), dim3(256), 0, stream>>>(xn16, xpw16, proj, (const float*)nullptr, MM, PP, DD);
  cvt_delta_kernel<<<dim3(1024), dim3(256), 0, stream>>>(proj, delta16);
  // dt = softplus(delta_r @ dt_proj_w^T + b) : (8192,2048,K=128)
  gemm_bt<1><<<dim3(1024), dim3(256), 0, stream>>>(delta16, dtw16, dt32, dtb, MM, DD, RR);
  // selective scan -> y (in d_out as scratch)
  scan_kernel<<<dim3(512), dim3(256), 0, stream>>>(dt32, xn16, proj, alog, out);
  // G = bf16(y + x*D)
  fuse_g_kernel<<<dim3(16384), dim3(256), 0, stream>>>(out, x, dpar, g16);
  // out = G @ out_proj_w^T : (8192,2048,K=2048)
  gemm_bt<0><<<dim3(1024), dim3(256), 0, stream>>>(g16, opw16, out, (const float*)nullptr, MM, DD, DD);
}